// Round 16
// baseline (595.259 us; speedup 1.0000x reference)
//
#include <hip/hip_runtime.h>
#include <hip/hip_bf16.h>
#include <hip/hip_fp16.h>

typedef unsigned int u32;
typedef unsigned short u16;
using f32x4 = __attribute__((ext_vector_type(4))) float;
using s16x8 = __attribute__((ext_vector_type(8))) short;
typedef _Float16 h16x2 __attribute__((ext_vector_type(2)));

#define NB 128
#define NH 8
#define LT 2050   // L + 2
#define ND 10     // DIM

#if defined(__has_builtin)
#if __has_builtin(__builtin_amdgcn_fdot2)
#define HAVE_FDOT2 1
#endif
#endif
#ifndef HAVE_FDOT2
#define HAVE_FDOT2 0
#endif

__device__ __forceinline__ u16 f2bf(float x){
  u32 u = __float_as_uint(x);
  u32 r = u + 0x7FFFu + ((u >> 16) & 1u);   // RNE
  return (u16)(r >> 16);
}
__device__ __forceinline__ u16 f2h(float x){
  return __half_as_ushort(__float2half(x));
}
__device__ __forceinline__ float h2f_lo(u32 v){
  __half_raw r; r.x = (u16)(v & 0xFFFFu); return __half2float(__half(r));
}
__device__ __forceinline__ float h2f_hi(u32 v){
  __half_raw r; r.x = (u16)(v >> 16); return __half2float(__half(r));
}
__device__ __forceinline__ float dot2p(u32 y, u32 w, float acc){
#if HAVE_FDOT2
  return __builtin_amdgcn_fdot2(__builtin_bit_cast(h16x2, y),
                                __builtin_bit_cast(h16x2, w), acc, false);
#else
  return fmaf(h2f_lo(y), h2f_lo(w), fmaf(h2f_hi(y), h2f_hi(w), acc));
#endif
}
// HW-verified on gfx950 (learn_hip T12/m240): packs 2 f32 -> 1 u32 of 2 bf16
__device__ __forceinline__ u32 cvtpk_bf16(float lo, float hi){
  u32 r;
  asm("v_cvt_pk_bf16_f32 %0, %1, %2" : "=v"(r) : "v"(lo), "v"(hi));
  return r;
}

// ---------------------------------------------------------------------------
// k_prep: fused independent prep roles, dispatched by blockIdx range:
//   [0,1025)      pack_y : depthwise convs -> padded f16-pair y tables
//   [1025,1035)   wpack  : projection weights -> f16 pairs
//   [1035,2059)   wobf   : W_O -> bf16
//   [2059,3467)   wc     : WC = W_V . v_fc_w (wave-parallel reduce)
#define PY_BLK 1025
#define WP_BLK 10
#define WO_BLK 1024
#define WC_BLK 1408
__global__ void k_prep(const float* __restrict__ Q, const float* __restrict__ Kin,
                       const float* __restrict__ w1, const float* __restrict__ b1,
                       const float* __restrict__ w2, const float* __restrict__ b2,
                       const float* __restrict__ pw1, const float* __restrict__ pw2,
                       const float* __restrict__ Wv, const float* __restrict__ vfw,
                       const float* __restrict__ vfb, const float* __restrict__ Wo,
                       u32* __restrict__ ypack, u32* __restrict__ wp1,
                       u32* __restrict__ wp2, u16* __restrict__ Wobf,
                       float* __restrict__ WCbc)
{
  int blk = blockIdx.x, tid = threadIdx.x;
  if (blk < PY_BLK){
    // ---- pack_y: per b [yq: 2113 x 5 u32][pad 3][yk: 2113 x 5][pad 3]
    //      rows 2050..2112 duplicate rows 0..62 (kills per-lane wrap).
    int g = blk * 256 + tid;
    if (g >= NB * LT) return;
    int b = g / LT, t = g - b * LT;
    const float* Qb = Q   + (size_t)b * ND * 2048;
    const float* Kb = Kin + (size_t)b * ND * 2048;
    u32 wq[5], wk[5];
#pragma unroll
    for (int i = 0; i < 5; i++){ wq[i] = 0; wk[i] = 0; }
#pragma unroll
    for (int u = 0; u < ND; u++){
      float aq = b1[u], ak = b2[u];
#pragma unroll
      for (int kk = 0; kk < 3; kk++){
        int x = t + kk - 2;                    // padding=2, kernel=3
        if (x >= 0 && x < 2048){
          aq = fmaf(w1[u*3+kk], Qb[u*2048 + x], aq);
          ak = fmaf(w2[u*3+kk], Kb[u*2048 + x], ak);
        }
      }
      wq[u >> 1] |= ((u32)f2h(aq)) << ((u & 1) * 16);
      wk[u >> 1] |= ((u32)f2h(ak)) << ((u & 1) * 16);
    }
    u32* basep = ypack + (size_t)b * 21136;
    u32* qr = basep + t * 5;
    u32* kr = basep + 10568 + t * 5;
#pragma unroll
    for (int i = 0; i < 5; i++){ qr[i] = wq[i]; kr[i] = wk[i]; }
    if (t < 63){
      u32* qr2 = basep + (t + 2050) * 5;
      u32* kr2 = basep + 10568 + (t + 2050) * 5;
#pragma unroll
      for (int i = 0; i < 5; i++){ qr2[i] = wq[i]; kr2[i] = wk[i]; }
    }
  } else if (blk < PY_BLK + WP_BLK){
    int id = (blk - PY_BLK) * 256 + tid;
    if (id >= 512 * 5) return;
    int c = id / 5, u = id - c * 5;
    wp1[id] = (u32)f2h(pw1[c*10 + 2*u]) | ((u32)f2h(pw1[c*10 + 2*u + 1]) << 16);
    wp2[id] = (u32)f2h(pw2[c*10 + 2*u]) | ((u32)f2h(pw2[c*10 + 2*u + 1]) << 16);
  } else if (blk < PY_BLK + WP_BLK + WO_BLK){
    int g = (blk - PY_BLK - WP_BLK) * 256 + tid;
    if (g < 512 * 512) Wobf[g] = f2bf(Wo[g]);
  } else {
    // ---- wc, one output per wave with shuffle-reduce
    int id = (blk - PY_BLK - WP_BLK - WO_BLK) * 4 + (tid >> 6);
    int lane = tid & 63;
    if (id >= 512 * 11) return;
    int o = id / 11, c = id - o * 11;
    const float* wr = Wv + (size_t)o * 512;
    float s = 0.f;
    if (c < 10){ for (int d = lane; d < 512; d += 64) s = fmaf(wr[d], vfw[d*10 + c], s); }
    else       { for (int d = lane; d < 512; d += 64) s = fmaf(wr[d], vfb[d], s); }
#pragma unroll
    for (int sh = 1; sh < 64; sh <<= 1) s += __shfl_xor(s, sh, 64);
    if (lane == 0) WCbc[id] = s;
  }
}

// ---------------------------------------------------------------------------
// P2b: vsT[b][h][lc][j] = v[b, lc, h*64+j]   (bf16)
__global__ void k_vst(const float* __restrict__ V, const float* __restrict__ WCbc,
                      u16* __restrict__ vsT)
{
  int g = blockIdx.x * 256 + threadIdx.x;
  if (g >= NB * NH * 20 * 64) return;
  int j  = g & 63;
  int lc = (g >> 6) % 20;
  int hh = (g / (64 * 20)) & 7;
  int b  = g / (64 * 20 * 8);
  int o  = hh * 64 + j;
  const float* wc = WCbc + o * 11;
  const float* vr = V + ((size_t)b * 20 + lc) * 10;
  float s = wc[10];
#pragma unroll
  for (int c = 0; c < 10; c++) s = fmaf(vr[c], wc[c], s);
  vsT[g] = f2bf(s);
}

// ---------------------------------------------------------------------------
// S: per (b,h): Gram operands generated from GLOBAL (L2-resident) padded f16
//    y tables — y is NOT staged in LDS. Rationale (R15 post-mortem): every
//    pipe <55% busy, occupancy pinned at 1 block/CU by the 84.5KB y table;
//    mod-8 swizzle makes the per-XCD y working set 16 x 84.5KB = 1.35MB < 4MB
//    L2, with ~32x reuse (L1 assist). Dropping the table halves LDS to
//    73.7KB -> 2 blocks/CU = 8 waves/SIMD, doubling latency hiding.
//    Otherwise identical to R12 (best measured): fdot2 inner product,
//    incremental (c0,t0) + readfirstlane, BK=128 double-buffer, aligned
//    144B tiles, operand prefetch, 16 waves = 4 row x 4 col quads.
// LDS map (bytes): set0 @0 (A0,B0,A1,B1 = 36864) | set1 @36864 -> 73728 total
//   epilogue aliases (set1 dead at tail; set0 holds tail tile):
//   vstl @36864 [32x144], Atl @41472 [64x144], Emax @50688 [4][64]f32,
//   Esum @51712 [4][64]f32
__launch_bounds__(1024, 8)
__global__ void k_scores(const u32* __restrict__ ypack,
                         const u32* __restrict__ wp1, const float* __restrict__ pb1,
                         const u32* __restrict__ wp2, const float* __restrict__ pb2,
                         const float* __restrict__ prev,
                         const u16* __restrict__ vsT,
                         float* __restrict__ attn_out, float* __restrict__ scores_out,
                         u16* __restrict__ ctx2)
{
  __shared__ uint4 smem_[4608];           // 73728 B
  char* sm  = (char*)smem_;

  int b    = blockIdx.x & (NB - 1);       // same-b blocks -> same XCD (mod-8)
  int h    = blockIdx.x >> 7;
  int tid  = threadIdx.x;
  int lane = tid & 63, w = tid >> 6;      // 16 waves
  int rw   = w & 3, cw = w >> 2;          // row-quad, col-quad

  const u32* ybase = ypack + (size_t)b * 21136;   // yq @0, yk @+10568 (u32)
  int laneu = lane * 5;                   // per-lane u32 offset within a row set

  // incremental (c0, t0) per m-slot; advance per kt: base += 32768
  int c0a[4], t0a[4];
#pragma unroll
  for (int m = 0; m < 4; m++){
    int base0 = (4 * w + m) * 512 + h * 64;   // < 32768
    c0a[m] = base0 / 2050;                    // once; magic-mul
    t0a[m] = base0 - c0a[m] * 2050;
  }

  // core per-m computation; c0s/t0s SCALARIZED (readfirstlane) -> s_loads;
  // y rows read from global (L2/L1), per-lane row t0s+lane.
  auto genm = [&](int m, float& aval, float& bval){
    int c0s = __builtin_amdgcn_readfirstlane(c0a[m]);
    int t0s = __builtin_amdgcn_readfirstlane(t0a[m]);
    const u32* yq = ybase + t0s * 5 + laneu;
    const u32* yk = yq + 10568;
    u32 qa[5], ka[5];
#pragma unroll
    for (int u = 0; u < 5; u++){ qa[u] = yq[u]; ka[u] = yk[u]; }
    if (t0s <= LT - 64){                   // uniform weight row (97%)
      aval = pb1[c0s]; bval = pb2[c0s];
      const u32* w1 = wp1 + c0s * 5;
      const u32* w2 = wp2 + c0s * 5;
#pragma unroll
      for (int u = 0; u < 5; u++){
        aval = dot2p(qa[u], w1[u], aval);
        bval = dot2p(ka[u], w2[u], bval);
      }
    } else {
      int c1s = c0s + 1;                   // never exceeds 511 (proven)
      bool wb = (t0s + lane >= LT);
      aval = wb ? pb1[c1s] : pb1[c0s];
      bval = wb ? pb2[c1s] : pb2[c0s];
#pragma unroll
      for (int u = 0; u < 5; u++){
        u32 w1u = wb ? wp1[c1s*5 + u] : wp1[c0s*5 + u];
        u32 w2u = wb ? wp2[c1s*5 + u] : wp2[c0s*5 + u];
        aval = dot2p(qa[u], w1u, aval);
        bval = dot2p(ka[u], w2u, bval);
      }
    }
  };
  auto adv = [&](int m){                   // state advance: base += 32768
    int tn = t0a[m] + 2018;
    if (tn >= 2050){ t0a[m] = tn - 2050; c0a[m] += 16; }
    else           { t0a[m] = tn;        c0a[m] += 15; }
  };
  auto genK = [&](char* Ap, char* Bp){     // one full kt tile, no k-guard
    float ava[4], avb[4];
#pragma unroll
    for (int m = 0; m < 4; m++){ genm(m, ava[m], avb[m]); adv(m); }
    *(uint2*)(Ap + lane * 144 + 8 * w) =
        make_uint2(cvtpk_bf16(ava[0], ava[1]), cvtpk_bf16(ava[2], ava[3]));
    *(uint2*)(Bp + lane * 144 + 8 * w) =
        make_uint2(cvtpk_bf16(avb[0], avb[1]), cvtpk_bf16(avb[2], avb[3]));
  };
  auto genTail = [&](char* Ap, char* Bp){  // kt 32: only kk 0,1 valid
    float ava[4], avb[4];
#pragma unroll
    for (int m = 0; m < 4; m++){
      ava[m] = 0.f; avb[m] = 0.f;
      if (4 * w + m < 2) genm(m, ava[m], avb[m]);
    }
    *(uint2*)(Ap + lane * 144 + 8 * w) =
        make_uint2(cvtpk_bf16(ava[0], ava[1]), cvtpk_bf16(ava[2], ava[3]));
    *(uint2*)(Bp + lane * 144 + 8 * w) =
        make_uint2(cvtpk_bf16(avb[0], avb[1]), cvtpk_bf16(avb[2], avb[3]));
  };

  char* cur = sm;                           // set0
  char* nxt = sm + 36864;                   // set1
  genK(cur, cur + 9216);                    // kt0 -> A0,B0
  genK(cur + 18432, cur + 27648);           // kt1 -> A1,B1
  __syncthreads();

  f32x4 acc = {0,0,0,0};
  int aoff = (16*rw + (lane & 15)) * 144 + ((lane >> 4) * 16);
  int boff = 9216 + (16*cw + (lane & 15)) * 144 + ((lane >> 4) * 16);

  for (int i = 0; i < 16; i++){
    // prefetch current set's 8 operand frags (oldest in LDS FIFO)
    const char* pa0 = cur + aoff;
    const char* pb0 = cur + boff;
    s16x8 a00 = *(const s16x8*)(pa0);
    s16x8 a01 = *(const s16x8*)(pa0 + 64);
    s16x8 b00 = *(const s16x8*)(pb0);
    s16x8 b01 = *(const s16x8*)(pb0 + 64);
    s16x8 a10 = *(const s16x8*)(pa0 + 18432);
    s16x8 a11 = *(const s16x8*)(pa0 + 18432 + 64);
    s16x8 b10 = *(const s16x8*)(pb0 + 18432);
    s16x8 b11 = *(const s16x8*)(pb0 + 18432 + 64);
    // generate next pair (kt 2i+2, 2i+3) / tail kt32
    if (i < 15){
      genK(nxt, nxt + 9216);
      genK(nxt + 18432, nxt + 27648);
    } else {
      genTail(nxt, nxt + 9216);
    }
    // Gram MFMA on prefetched frags
    acc = __builtin_amdgcn_mfma_f32_16x16x32_bf16(a00, b00, acc, 0, 0, 0);
    acc = __builtin_amdgcn_mfma_f32_16x16x32_bf16(a01, b01, acc, 0, 0, 0);
    acc = __builtin_amdgcn_mfma_f32_16x16x32_bf16(a10, b10, acc, 0, 0, 0);
    acc = __builtin_amdgcn_mfma_f32_16x16x32_bf16(a11, b11, acc, 0, 0, 0);
    __syncthreads();
    char* ts = cur; cur = nxt; nxt = ts;
  }
  { // tail: kt32 lives in cur (=set0) slot0
    const char* pa0 = cur + aoff;
    const char* pb0 = cur + boff;
    s16x8 a00 = *(const s16x8*)(pa0);
    s16x8 a01 = *(const s16x8*)(pa0 + 64);
    s16x8 b00 = *(const s16x8*)(pb0);
    s16x8 b01 = *(const s16x8*)(pb0 + 64);
    acc = __builtin_amdgcn_mfma_f32_16x16x32_bf16(a00, b00, acc, 0, 0, 0);
    acc = __builtin_amdgcn_mfma_f32_16x16x32_bf16(a01, b01, acc, 0, 0, 0);
  }

  // ---- epilogue: scratch lives in set1 (dead); set0 holds the tail tile
  char*  vstl = sm + 36864;                 // [32][144] bf16
  char*  Atl  = sm + 41472;                 // attn bf16 tile [64][144]
  float* Emax = (float*)(sm + 50688);       // [4][64]
  float* Esum = (float*)(sm + 51712);       // [4][64]

  if (tid < 256){                           // stage v_s^T rows (20 real, pad 32)
    int row = tid >> 3, c8 = tid & 7;
    uint4 v = make_uint4(0, 0, 0, 0);
    if (row < 20)
      v = *(const uint4*)((const char*)vsT + ((size_t)(b*NH + h)) * 2560 + row * 128 + c8 * 16);
    *(uint4*)(vstl + row * 144 + c8 * 16) = v;
  }

  int ib = 16 * rw + ((lane >> 4) << 2);    // C/D row base
  int jb = 16 * cw + (lane & 15);           // C/D col (this wave's quarter)
  const float* prevb = prev       + ((size_t)(b*NH + h)) * 4096;
  float*       scob  = scores_out + ((size_t)(b*NH + h)) * 4096;
  float*       atob  = attn_out   + ((size_t)(b*NH + h)) * 4096;

  float sc[4];
#pragma unroll
  for (int r = 0; r < 4; r++)
    sc[r] = acc[r] * 0.125f + prevb[(ib + r) * 64 + jb];

  float pm[4];
#pragma unroll
  for (int r = 0; r < 4; r++) pm[r] = sc[r];
#pragma unroll
  for (int s = 1; s < 16; s <<= 1)
#pragma unroll
    for (int r = 0; r < 4; r++) pm[r] = fmaxf(pm[r], __shfl_xor(pm[r], s, 64));
  if ((lane & 15) == 0){
#pragma unroll
    for (int r = 0; r < 4; r++) Emax[cw * 64 + ib + r] = pm[r];
  }
#pragma unroll
  for (int r = 0; r < 4; r++)
    scob[(ib + r) * 64 + jb] = sc[r];
  __syncthreads();

  float e[4], ps[4];
#pragma unroll
  for (int r = 0; r < 4; r++){
    int i = ib + r;
    float m4 = fmaxf(fmaxf(Emax[i], Emax[64 + i]), fmaxf(Emax[128 + i], Emax[192 + i]));
    e[r] = __expf(sc[r] - m4);
    ps[r] = e[r];
  }
#pragma unroll
  for (int s = 1; s < 16; s <<= 1)
#pragma unroll
    for (int r = 0; r < 4; r++) ps[r] += __shfl_xor(ps[r], s, 64);
  if ((lane & 15) == 0){
#pragma unroll
    for (int r = 0; r < 4; r++) Esum[cw * 64 + ib + r] = ps[r];
  }
  __syncthreads();

#pragma unroll
  for (int r = 0; r < 4; r++){
    int i = ib + r;
    float inv = 1.0f / (Esum[i] + Esum[64 + i] + Esum[128 + i] + Esum[192 + i]);
    float at = e[r] * inv;
    atob[i * 64 + jb] = at;
    *(u16*)(Atl + i * 144 + jb * 2) = f2bf(at);
  }
  __syncthreads();

  // ---- context = attn @ v_s : waves 0..7
  if (w < 8){
    f32x4 ca = {0,0,0,0};
    const char* pa = Atl  + (16*rw + (lane & 15)) * 144 + ((lane >> 4) * 16);
    const char* pv = vstl + (16*(w >> 2) + (lane & 15)) * 144 + ((lane >> 4) * 16);
#pragma unroll
    for (int ks = 0; ks < 2; ks++){
      s16x8 av = *(const s16x8*)(pa + ks * 64);
      s16x8 bv = *(const s16x8*)(pv + ks * 64);
      ca = __builtin_amdgcn_mfma_f32_16x16x32_bf16(av, bv, ca, 0, 0, 0);
    }
    u16* ctxb = ctx2 + (size_t)b * 10240;
    int lc = 16 * (w >> 2) + (lane & 15);
    if (lc < 20){
#pragma unroll
      for (int r = 0; r < 4; r++)
        ctxb[(ib + r) * 160 + h * 20 + lc] = f2bf(ca[r]);
    }
  }
}

// ---------------------------------------------------------------------------
// O: output[b] = ctx2[b] (20x512, pad 32) @ W_O^T via MFMA, K=512.
//    256 blocks: (b, half) with each block covering 256 output d's.
__launch_bounds__(256)
__global__ void k_out(const u16* __restrict__ ctx2, const u16* __restrict__ Wobf,
                      float* __restrict__ outp)
{
  __shared__ u16 ctxl[32 * 520];
  int b = blockIdx.x >> 1, half = blockIdx.x & 1;
  int tid = threadIdx.x;
  for (int idx = tid; idx < 2048; idx += 256){
    int row = idx >> 6, c8 = idx & 63;
    uint4 v = make_uint4(0, 0, 0, 0);
    if (row < 20)
      v = *(const uint4*)((const char*)ctx2 + (size_t)b * 20480 + row * 1024 + c8 * 16);
    *(uint4*)((char*)ctxl + row * 1040 + c8 * 16) = v;
  }
  __syncthreads();
  int lane = tid & 63, w = tid >> 6;
  f32x4 acc[2][4];
#pragma unroll
  for (int m2 = 0; m2 < 2; m2++)
#pragma unroll
    for (int n = 0; n < 4; n++) acc[m2][n] = (f32x4){0,0,0,0};

  for (int ks = 0; ks < 16; ks++){
    s16x8 a0 = *(const s16x8*)((char*)ctxl + (lane & 15) * 1040        + ks * 64 + ((lane >> 4) * 16));
    s16x8 a1 = *(const s16x8*)((char*)ctxl + (16 + (lane & 15)) * 1040 + ks * 64 + ((lane >> 4) * 16));
#pragma unroll
    for (int n = 0; n < 4; n++){
      int d = half * 256 + w * 64 + n * 16 + (lane & 15);
      s16x8 bb = *(const s16x8*)((const char*)Wobf + (size_t)d * 1024 + ks * 64 + ((lane >> 4) * 16));
      acc[0][n] = __builtin_amdgcn_mfma_f32_16x16x32_bf16(a0, bb, acc[0][n], 0, 0, 0);
      acc[1][n] = __builtin_amdgcn_mfma_f32_16x16x32_bf16(a1, bb, acc[1][n], 0, 0, 0);
    }
  }
  float* ob = outp + (size_t)b * 10240;
#pragma unroll
  for (int m2 = 0; m2 < 2; m2++){
    int lp0 = m2 * 16 + ((lane >> 4) << 2);
    if (lp0 >= 20) continue;
#pragma unroll
    for (int n = 0; n < 4; n++){
      int d = half * 256 + w * 64 + n * 16 + (lane & 15);
#pragma unroll
      for (int r = 0; r < 4; r++){
        int lp = lp0 + r;
        if (lp < 20) ob[lp * 512 + d] = acc[m2][n][r];
      }
    }
  }
}

// ---------------------------------------------------------------------------
extern "C" void kernel_launch(void* const* d_in, const int* in_sizes, int n_in,
                              void* d_out, int out_size, void* d_ws, size_t ws_size,
                              hipStream_t stream)
{
  (void)in_sizes; (void)n_in; (void)out_size; (void)ws_size;
  const float* Q      = (const float*)d_in[0];
  const float* K      = (const float*)d_in[1];
  const float* V      = (const float*)d_in[2];
  const float* prev   = (const float*)d_in[3];
  const float* c1w    = (const float*)d_in[4];
  const float* c1b    = (const float*)d_in[5];
  const float* c1pw   = (const float*)d_in[6];
  const float* c1pb   = (const float*)d_in[7];
  const float* c2w    = (const float*)d_in[8];
  const float* c2b    = (const float*)d_in[9];
  const float* c2pw   = (const float*)d_in[10];
  const float* c2pb   = (const float*)d_in[11];
  const float* vfw    = (const float*)d_in[12];
  const float* vfb    = (const float*)d_in[13];
  const float* Wv     = (const float*)d_in[14];
  const float* Wo     = (const float*)d_in[15];

  char* ws = (char*)d_ws;
  u32*   ypack = (u32*)(ws + 0);            // 128 * 84544 = 10,821,632 B
  u32*   wp1   = (u32*)(ws + 10821632);     //     10,240 B
  u32*   wp2   = (u32*)(ws + 10831872);     //     10,240 B
  float* WCbc  = (float*)(ws + 10842112);   //     22,528 B
  u16*   vsT   = (u16*)(ws + 10864640);     //  2,621,440 B
  u16*   Wobf  = (u16*)(ws + 13486080);     //    524,288 B
  u16*   ctx2  = (u16*)(ws + 14010368);     //  2,621,440 B (total ~16.6 MB)

  float* outp     = (float*)d_out;
  float* attn_o   = outp + 1310720;
  float* scores_o = outp + 5505024;

  k_prep  <<<dim3(PY_BLK + WP_BLK + WO_BLK + WC_BLK), dim3(256), 0, stream>>>(
      Q, K, c1w, c1b, c2w, c2b, c1pw, c2pw, Wv, vfw, vfb, Wo,
      ypack, wp1, wp2, Wobf, WCbc);
  k_vst   <<<dim3(5120), dim3(256), 0, stream>>>(V, WCbc, vsT);
  k_scores<<<dim3(1024), dim3(1024), 0, stream>>>(ypack, wp1, c1pb, wp2, c2pb,
                                                  prev, vsT, attn_o, scores_o, ctx2);
  k_out   <<<dim3(256),  dim3(256), 0, stream>>>(ctx2, Wobf, outp);
}

// Round 19
// 233.488 us; speedup vs baseline: 2.5494x; 2.5494x over previous
//
#include <hip/hip_runtime.h>
#include <hip/hip_bf16.h>
#include <hip/hip_fp16.h>

typedef unsigned int u32;
typedef unsigned short u16;
using f32x4 = __attribute__((ext_vector_type(4))) float;
using s16x8 = __attribute__((ext_vector_type(8))) short;
typedef _Float16 h16x2 __attribute__((ext_vector_type(2)));

#define NB 128
#define NH 8
#define LT 2050   // L + 2
#define ND 10     // DIM

#if defined(__has_builtin)
#if __has_builtin(__builtin_amdgcn_fdot2)
#define HAVE_FDOT2 1
#endif
#endif
#ifndef HAVE_FDOT2
#define HAVE_FDOT2 0
#endif

__device__ __forceinline__ u16 f2bf(float x){
  u32 u = __float_as_uint(x);
  u32 r = u + 0x7FFFu + ((u >> 16) & 1u);   // RNE
  return (u16)(r >> 16);
}
__device__ __forceinline__ u16 f2h(float x){
  return __half_as_ushort(__float2half(x));
}
__device__ __forceinline__ float h2f_lo(u32 v){
  __half_raw r; r.x = (u16)(v & 0xFFFFu); return __half2float(__half(r));
}
__device__ __forceinline__ float h2f_hi(u32 v){
  __half_raw r; r.x = (u16)(v >> 16); return __half2float(__half(r));
}
__device__ __forceinline__ float dot2p(u32 y, u32 w, float acc){
#if HAVE_FDOT2
  return __builtin_amdgcn_fdot2(__builtin_bit_cast(h16x2, y),
                                __builtin_bit_cast(h16x2, w), acc, false);
#else
  return fmaf(h2f_lo(y), h2f_lo(w), fmaf(h2f_hi(y), h2f_hi(w), acc));
#endif
}
// HW-verified on gfx950 (learn_hip T12/m240): packs 2 f32 -> 1 u32 of 2 bf16
__device__ __forceinline__ u32 cvtpk_bf16(float lo, float hi){
  u32 r;
  asm("v_cvt_pk_bf16_f32 %0, %1, %2" : "=v"(r) : "v"(lo), "v"(hi));
  return r;
}

// ---------------------------------------------------------------------------
// k_prep: fused independent prep roles, dispatched by blockIdx range:
//   [0,1025)      pack_y : depthwise convs -> padded f16-pair y tables
//   [1025,1035)   wpack  : projection weights -> f16 pairs
//   [1035,2059)   wobf   : W_O -> bf16
//   [2059,3467)   wc     : WC = W_V . v_fc_w (wave-parallel reduce)
#define PY_BLK 1025
#define WP_BLK 10
#define WO_BLK 1024
#define WC_BLK 1408
__global__ void k_prep(const float* __restrict__ Q, const float* __restrict__ Kin,
                       const float* __restrict__ w1, const float* __restrict__ b1,
                       const float* __restrict__ w2, const float* __restrict__ b2,
                       const float* __restrict__ pw1, const float* __restrict__ pw2,
                       const float* __restrict__ Wv, const float* __restrict__ vfw,
                       const float* __restrict__ vfb, const float* __restrict__ Wo,
                       u32* __restrict__ ypack, u32* __restrict__ wp1,
                       u32* __restrict__ wp2, u16* __restrict__ Wobf,
                       float* __restrict__ WCbc)
{
  int blk = blockIdx.x, tid = threadIdx.x;
  if (blk < PY_BLK){
    // ---- pack_y: per b [yq: 2113 x 5 u32][pad 3][yk: 2113 x 5][pad 3]
    //      rows 2050..2112 duplicate rows 0..62 (kills per-lane wrap).
    int g = blk * 256 + tid;
    if (g >= NB * LT) return;
    int b = g / LT, t = g - b * LT;
    const float* Qb = Q   + (size_t)b * ND * 2048;
    const float* Kb = Kin + (size_t)b * ND * 2048;
    u32 wq[5], wk[5];
#pragma unroll
    for (int i = 0; i < 5; i++){ wq[i] = 0; wk[i] = 0; }
#pragma unroll
    for (int u = 0; u < ND; u++){
      float aq = b1[u], ak = b2[u];
#pragma unroll
      for (int kk = 0; kk < 3; kk++){
        int x = t + kk - 2;                    // padding=2, kernel=3
        if (x >= 0 && x < 2048){
          aq = fmaf(w1[u*3+kk], Qb[u*2048 + x], aq);
          ak = fmaf(w2[u*3+kk], Kb[u*2048 + x], ak);
        }
      }
      wq[u >> 1] |= ((u32)f2h(aq)) << ((u & 1) * 16);
      wk[u >> 1] |= ((u32)f2h(ak)) << ((u & 1) * 16);
    }
    u32* basep = ypack + (size_t)b * 21136;
    u32* qr = basep + t * 5;
    u32* kr = basep + 10568 + t * 5;
#pragma unroll
    for (int i = 0; i < 5; i++){ qr[i] = wq[i]; kr[i] = wk[i]; }
    if (t < 63){
      u32* qr2 = basep + (t + 2050) * 5;
      u32* kr2 = basep + 10568 + (t + 2050) * 5;
#pragma unroll
      for (int i = 0; i < 5; i++){ qr2[i] = wq[i]; kr2[i] = wk[i]; }
    }
  } else if (blk < PY_BLK + WP_BLK){
    int id = (blk - PY_BLK) * 256 + tid;
    if (id >= 512 * 5) return;
    int c = id / 5, u = id - c * 5;
    wp1[id] = (u32)f2h(pw1[c*10 + 2*u]) | ((u32)f2h(pw1[c*10 + 2*u + 1]) << 16);
    wp2[id] = (u32)f2h(pw2[c*10 + 2*u]) | ((u32)f2h(pw2[c*10 + 2*u + 1]) << 16);
  } else if (blk < PY_BLK + WP_BLK + WO_BLK){
    int g = (blk - PY_BLK - WP_BLK) * 256 + tid;
    if (g < 512 * 512) Wobf[g] = f2bf(Wo[g]);
  } else {
    // ---- wc, one output per wave with shuffle-reduce
    int id = (blk - PY_BLK - WP_BLK - WO_BLK) * 4 + (tid >> 6);
    int lane = tid & 63;
    if (id >= 512 * 11) return;
    int o = id / 11, c = id - o * 11;
    const float* wr = Wv + (size_t)o * 512;
    float s = 0.f;
    if (c < 10){ for (int d = lane; d < 512; d += 64) s = fmaf(wr[d], vfw[d*10 + c], s); }
    else       { for (int d = lane; d < 512; d += 64) s = fmaf(wr[d], vfb[d], s); }
#pragma unroll
    for (int sh = 1; sh < 64; sh <<= 1) s += __shfl_xor(s, sh, 64);
    if (lane == 0) WCbc[id] = s;
  }
}

// ---------------------------------------------------------------------------
// P2b: vsT[b][h][lc][j] = v[b, lc, h*64+j]   (bf16)
__global__ void k_vst(const float* __restrict__ V, const float* __restrict__ WCbc,
                      u16* __restrict__ vsT)
{
  int g = blockIdx.x * 256 + threadIdx.x;
  if (g >= NB * NH * 20 * 64) return;
  int j  = g & 63;
  int lc = (g >> 6) % 20;
  int hh = (g / (64 * 20)) & 7;
  int b  = g / (64 * 20 * 8);
  int o  = hh * 64 + j;
  const float* wc = WCbc + o * 11;
  const float* vr = V + ((size_t)b * 20 + lc) * 10;
  float s = wc[10];
#pragma unroll
  for (int c = 0; c < 10; c++) s = fmaf(vr[c], wc[c], s);
  vsT[g] = f2bf(s);
}

// ---------------------------------------------------------------------------
// S: per (b,h): on-the-fly Gram operands from padded LDS f16 y (fdot2),
//    incremental (c0,t0) state + readfirstlane scalarization, BK=128
//    (2 kt per barrier phase), MFMA operand prefetch before gen,
//    16 waves = 4 row x 4 col quads.  [R12 configuration — best measured:
//    k_scores 217.4 us; R14 burst-load, R15 pk_fma, R16 global-y all
//    regressed; conflicts at b128 floor; latency-bound at 1 block/CU.]
// LDS map (bytes):
//   0      yq   [2113 x 20]          42260 (+12 pad)
//   42272  yk   [2113 x 20]          42260 (+12 pad -> 84544)
//   84544  set0: A0,B0,A1,B1  4 x 9216 = 36864
//   121408 set1: A0,B0,A1,B1  4 x 9216 = 36864  -> total 158272
//   epilogue aliases (y dead): vstl @17408 [32x144], Emax @22016 [4][64]f32,
//                              Esum @23040 [4][64]f32; Atl @84544 [64][144]
__launch_bounds__(1024, 1)
__global__ void k_scores(const u32* __restrict__ ypack,
                         const u32* __restrict__ wp1, const float* __restrict__ pb1,
                         const u32* __restrict__ wp2, const float* __restrict__ pb2,
                         const float* __restrict__ prev,
                         const u16* __restrict__ vsT,
                         float* __restrict__ attn_out, float* __restrict__ scores_out,
                         u16* __restrict__ ctx2)
{
  __shared__ uint4 smem_[9892];           // 158272 B
  char* sm  = (char*)smem_;

  int b    = blockIdx.x & (NB - 1);       // same-b blocks -> same XCD (mod-8)
  int h    = blockIdx.x >> 7;
  int tid  = threadIdx.x;
  int lane = tid & 63, w = tid >> 6;      // 16 waves
  int rw   = w & 3, cw = w >> 2;          // row-quad, col-quad
  int laneoff = lane * 20;                // per-lane y byte offset

  { // stage padded y (84544 B contiguous per b) as uint4, stride-1
    const uint4* src = (const uint4*)(ypack + (size_t)b * 21136);
    uint4* dstl = (uint4*)sm;
    for (int i = tid; i < 5284; i += 1024) dstl[i] = src[i];
  }

  // incremental (c0, t0) per m-slot; advance per kt: base += 32768
  int c0a[4], t0a[4];
#pragma unroll
  for (int m = 0; m < 4; m++){
    int base0 = (4 * w + m) * 512 + h * 64;   // < 32768
    c0a[m] = base0 / 2050;                    // once; magic-mul
    t0a[m] = base0 - c0a[m] * 2050;
  }

  // core per-m computation; c0s/t0s SCALARIZED (readfirstlane) -> s_loads
  auto genm = [&](int m, float& aval, float& bval){
    int c0s = __builtin_amdgcn_readfirstlane(c0a[m]);
    int t0s = __builtin_amdgcn_readfirstlane(t0a[m]);
    const u32* yq = (const u32*)(sm + t0s * 20 + laneoff);
    const u32* yk = (const u32*)(sm + 42272 + t0s * 20 + laneoff);
    u32 qa[5], ka[5];
#pragma unroll
    for (int u = 0; u < 5; u++){ qa[u] = yq[u]; ka[u] = yk[u]; }
    if (t0s <= LT - 64){                   // uniform weight row (97%)
      aval = pb1[c0s]; bval = pb2[c0s];
      const u32* w1 = wp1 + c0s * 5;
      const u32* w2 = wp2 + c0s * 5;
#pragma unroll
      for (int u = 0; u < 5; u++){
        aval = dot2p(qa[u], w1[u], aval);
        bval = dot2p(ka[u], w2[u], bval);
      }
    } else {
      int c1s = c0s + 1;                   // never exceeds 511 (proven)
      bool wb = (t0s + lane >= LT);
      aval = wb ? pb1[c1s] : pb1[c0s];
      bval = wb ? pb2[c1s] : pb2[c0s];
#pragma unroll
      for (int u = 0; u < 5; u++){
        u32 w1u = wb ? wp1[c1s*5 + u] : wp1[c0s*5 + u];
        u32 w2u = wb ? wp2[c1s*5 + u] : wp2[c0s*5 + u];
        aval = dot2p(qa[u], w1u, aval);
        bval = dot2p(ka[u], w2u, bval);
      }
    }
  };
  auto adv = [&](int m){                   // state advance: base += 32768
    int tn = t0a[m] + 2018;
    if (tn >= 2050){ t0a[m] = tn - 2050; c0a[m] += 16; }
    else           { t0a[m] = tn;        c0a[m] += 15; }
  };
  auto genK = [&](char* Ap, char* Bp){     // one full kt tile, no k-guard
    float ava[4], avb[4];
#pragma unroll
    for (int m = 0; m < 4; m++){ genm(m, ava[m], avb[m]); adv(m); }
    *(uint2*)(Ap + lane * 144 + 8 * w) =
        make_uint2(cvtpk_bf16(ava[0], ava[1]), cvtpk_bf16(ava[2], ava[3]));
    *(uint2*)(Bp + lane * 144 + 8 * w) =
        make_uint2(cvtpk_bf16(avb[0], avb[1]), cvtpk_bf16(avb[2], avb[3]));
  };
  auto genTail = [&](char* Ap, char* Bp){  // kt 32: only kk 0,1 valid
    float ava[4], avb[4];
#pragma unroll
    for (int m = 0; m < 4; m++){
      ava[m] = 0.f; avb[m] = 0.f;
      if (4 * w + m < 2) genm(m, ava[m], avb[m]);
    }
    *(uint2*)(Ap + lane * 144 + 8 * w) =
        make_uint2(cvtpk_bf16(ava[0], ava[1]), cvtpk_bf16(ava[2], ava[3]));
    *(uint2*)(Bp + lane * 144 + 8 * w) =
        make_uint2(cvtpk_bf16(avb[0], avb[1]), cvtpk_bf16(avb[2], avb[3]));
  };

  __syncthreads();                          // y staged
  char* cur = sm + 84544;                   // set0
  char* nxt = sm + 121408;                  // set1
  genK(cur, cur + 9216);                    // kt0 -> A0,B0
  genK(cur + 18432, cur + 27648);           // kt1 -> A1,B1
  __syncthreads();

  f32x4 acc = {0,0,0,0};
  int aoff = (16*rw + (lane & 15)) * 144 + ((lane >> 4) * 16);
  int boff = 9216 + (16*cw + (lane & 15)) * 144 + ((lane >> 4) * 16);

  for (int i = 0; i < 16; i++){
    // prefetch current set's 8 operand frags (oldest in LDS FIFO)
    const char* pa0 = cur + aoff;
    const char* pb0 = cur + boff;
    s16x8 a00 = *(const s16x8*)(pa0);
    s16x8 a01 = *(const s16x8*)(pa0 + 64);
    s16x8 b00 = *(const s16x8*)(pb0);
    s16x8 b01 = *(const s16x8*)(pb0 + 64);
    s16x8 a10 = *(const s16x8*)(pa0 + 18432);
    s16x8 a11 = *(const s16x8*)(pa0 + 18432 + 64);
    s16x8 b10 = *(const s16x8*)(pb0 + 18432);
    s16x8 b11 = *(const s16x8*)(pb0 + 18432 + 64);
    // generate next pair (kt 2i+2, 2i+3) / tail kt32
    if (i < 15){
      genK(nxt, nxt + 9216);
      genK(nxt + 18432, nxt + 27648);
    } else {
      genTail(nxt, nxt + 9216);
    }
    // Gram MFMA on prefetched frags
    acc = __builtin_amdgcn_mfma_f32_16x16x32_bf16(a00, b00, acc, 0, 0, 0);
    acc = __builtin_amdgcn_mfma_f32_16x16x32_bf16(a01, b01, acc, 0, 0, 0);
    acc = __builtin_amdgcn_mfma_f32_16x16x32_bf16(a10, b10, acc, 0, 0, 0);
    acc = __builtin_amdgcn_mfma_f32_16x16x32_bf16(a11, b11, acc, 0, 0, 0);
    __syncthreads();
    char* ts = cur; cur = nxt; nxt = ts;
  }
  { // tail: kt32 lives in cur slot0
    const char* pa0 = cur + aoff;
    const char* pb0 = cur + boff;
    s16x8 a00 = *(const s16x8*)(pa0);
    s16x8 a01 = *(const s16x8*)(pa0 + 64);
    s16x8 b00 = *(const s16x8*)(pb0);
    s16x8 b01 = *(const s16x8*)(pb0 + 64);
    acc = __builtin_amdgcn_mfma_f32_16x16x32_bf16(a00, b00, acc, 0, 0, 0);
    acc = __builtin_amdgcn_mfma_f32_16x16x32_bf16(a01, b01, acc, 0, 0, 0);
  }

  // ---- epilogue (y region dead)
  char*  vstl = sm + 17408;                 // [32][144] bf16
  float* Emax = (float*)(sm + 22016);       // [4][64]
  float* Esum = (float*)(sm + 23040);       // [4][64]
  char*  Atl  = sm + 84544;                 // attn bf16 tile [64][144]

  if (tid < 256){                           // stage v_s^T rows (20 real, pad 32)
    int row = tid >> 3, c8 = tid & 7;
    uint4 v = make_uint4(0, 0, 0, 0);
    if (row < 20)
      v = *(const uint4*)((const char*)vsT + ((size_t)(b*NH + h)) * 2560 + row * 128 + c8 * 16);
    *(uint4*)(vstl + row * 144 + c8 * 16) = v;
  }

  int ib = 16 * rw + ((lane >> 4) << 2);    // C/D row base
  int jb = 16 * cw + (lane & 15);           // C/D col (this wave's quarter)
  const float* prevb = prev       + ((size_t)(b*NH + h)) * 4096;
  float*       scob  = scores_out + ((size_t)(b*NH + h)) * 4096;
  float*       atob  = attn_out   + ((size_t)(b*NH + h)) * 4096;

  float sc[4];
#pragma unroll
  for (int r = 0; r < 4; r++)
    sc[r] = acc[r] * 0.125f + prevb[(ib + r) * 64 + jb];

  float pm[4];
#pragma unroll
  for (int r = 0; r < 4; r++) pm[r] = sc[r];
#pragma unroll
  for (int s = 1; s < 16; s <<= 1)
#pragma unroll
    for (int r = 0; r < 4; r++) pm[r] = fmaxf(pm[r], __shfl_xor(pm[r], s, 64));
  if ((lane & 15) == 0){
#pragma unroll
    for (int r = 0; r < 4; r++) Emax[cw * 64 + ib + r] = pm[r];
  }
#pragma unroll
  for (int r = 0; r < 4; r++)
    scob[(ib + r) * 64 + jb] = sc[r];
  __syncthreads();

  float e[4], ps[4];
#pragma unroll
  for (int r = 0; r < 4; r++){
    int i = ib + r;
    float m4 = fmaxf(fmaxf(Emax[i], Emax[64 + i]), fmaxf(Emax[128 + i], Emax[192 + i]));
    e[r] = __expf(sc[r] - m4);
    ps[r] = e[r];
  }
#pragma unroll
  for (int s = 1; s < 16; s <<= 1)
#pragma unroll
    for (int r = 0; r < 4; r++) ps[r] += __shfl_xor(ps[r], s, 64);
  if ((lane & 15) == 0){
#pragma unroll
    for (int r = 0; r < 4; r++) Esum[cw * 64 + ib + r] = ps[r];
  }
  __syncthreads();

#pragma unroll
  for (int r = 0; r < 4; r++){
    int i = ib + r;
    float inv = 1.0f / (Esum[i] + Esum[64 + i] + Esum[128 + i] + Esum[192 + i]);
    float at = e[r] * inv;
    atob[i * 64 + jb] = at;
    *(u16*)(Atl + i * 144 + jb * 2) = f2bf(at);
  }
  __syncthreads();

  // ---- context = attn @ v_s : waves 0..7
  if (w < 8){
    f32x4 ca = {0,0,0,0};
    const char* pa = Atl  + (16*rw + (lane & 15)) * 144 + ((lane >> 4) * 16);
    const char* pv = vstl + (16*(w >> 2) + (lane & 15)) * 144 + ((lane >> 4) * 16);
#pragma unroll
    for (int ks = 0; ks < 2; ks++){
      s16x8 av = *(const s16x8*)(pa + ks * 64);
      s16x8 bv = *(const s16x8*)(pv + ks * 64);
      ca = __builtin_amdgcn_mfma_f32_16x16x32_bf16(av, bv, ca, 0, 0, 0);
    }
    u16* ctxb = ctx2 + (size_t)b * 10240;
    int lc = 16 * (w >> 2) + (lane & 15);
    if (lc < 20){
#pragma unroll
      for (int r = 0; r < 4; r++)
        ctxb[(ib + r) * 160 + h * 20 + lc] = f2bf(ca[r]);
    }
  }
}

// ---------------------------------------------------------------------------
// O: output[b] = ctx2[b] (20x512, pad 32) @ W_O^T via MFMA, K=512.
//    256 blocks: (b, half) with each block covering 256 output d's.
__launch_bounds__(256)
__global__ void k_out(const u16* __restrict__ ctx2, const u16* __restrict__ Wobf,
                      float* __restrict__ outp)
{
  __shared__ u16 ctxl[32 * 520];
  int b = blockIdx.x >> 1, half = blockIdx.x & 1;
  int tid = threadIdx.x;
  for (int idx = tid; idx < 2048; idx += 256){
    int row = idx >> 6, c8 = idx & 63;
    uint4 v = make_uint4(0, 0, 0, 0);
    if (row < 20)
      v = *(const uint4*)((const char*)ctx2 + (size_t)b * 20480 + row * 1024 + c8 * 16);
    *(uint4*)((char*)ctxl + row * 1040 + c8 * 16) = v;
  }
  __syncthreads();
  int lane = tid & 63, w = tid >> 6;
  f32x4 acc[2][4];
#pragma unroll
  for (int m2 = 0; m2 < 2; m2++)
#pragma unroll
    for (int n = 0; n < 4; n++) acc[m2][n] = (f32x4){0,0,0,0};

  for (int ks = 0; ks < 16; ks++){
    s16x8 a0 = *(const s16x8*)((char*)ctxl + (lane & 15) * 1040        + ks * 64 + ((lane >> 4) * 16));
    s16x8 a1 = *(const s16x8*)((char*)ctxl + (16 + (lane & 15)) * 1040 + ks * 64 + ((lane >> 4) * 16));
#pragma unroll
    for (int n = 0; n < 4; n++){
      int d = half * 256 + w * 64 + n * 16 + (lane & 15);
      s16x8 bb = *(const s16x8*)((const char*)Wobf + (size_t)d * 1024 + ks * 64 + ((lane >> 4) * 16));
      acc[0][n] = __builtin_amdgcn_mfma_f32_16x16x32_bf16(a0, bb, acc[0][n], 0, 0, 0);
      acc[1][n] = __builtin_amdgcn_mfma_f32_16x16x32_bf16(a1, bb, acc[1][n], 0, 0, 0);
    }
  }
  float* ob = outp + (size_t)b * 10240;
#pragma unroll
  for (int m2 = 0; m2 < 2; m2++){
    int lp0 = m2 * 16 + ((lane >> 4) << 2);
    if (lp0 >= 20) continue;
#pragma unroll
    for (int n = 0; n < 4; n++){
      int d = half * 256 + w * 64 + n * 16 + (lane & 15);
#pragma unroll
      for (int r = 0; r < 4; r++){
        int lp = lp0 + r;
        if (lp < 20) ob[lp * 512 + d] = acc[m2][n][r];
      }
    }
  }
}

// ---------------------------------------------------------------------------
extern "C" void kernel_launch(void* const* d_in, const int* in_sizes, int n_in,
                              void* d_out, int out_size, void* d_ws, size_t ws_size,
                              hipStream_t stream)
{
  (void)in_sizes; (void)n_in; (void)out_size; (void)ws_size;
  const float* Q      = (const float*)d_in[0];
  const float* K      = (const float*)d_in[1];
  const float* V      = (const float*)d_in[2];
  const float* prev   = (const float*)d_in[3];
  const float* c1w    = (const float*)d_in[4];
  const float* c1b    = (const float*)d_in[5];
  const float* c1pw   = (const float*)d_in[6];
  const float* c1pb   = (const float*)d_in[7];
  const float* c2w    = (const float*)d_in[8];
  const float* c2b    = (const float*)d_in[9];
  const float* c2pw   = (const float*)d_in[10];
  const float* c2pb   = (const float*)d_in[11];
  const float* vfw    = (const float*)d_in[12];
  const float* vfb    = (const float*)d_in[13];
  const float* Wv     = (const float*)d_in[14];
  const float* Wo     = (const float*)d_in[15];

  char* ws = (char*)d_ws;
  u32*   ypack = (u32*)(ws + 0);            // 128 * 84544 = 10,821,632 B
  u32*   wp1   = (u32*)(ws + 10821632);     //     10,240 B
  u32*   wp2   = (u32*)(ws + 10831872);     //     10,240 B
  float* WCbc  = (float*)(ws + 10842112);   //     22,528 B
  u16*   vsT   = (u16*)(ws + 10864640);     //  2,621,440 B
  u16*   Wobf  = (u16*)(ws + 13486080);     //    524,288 B
  u16*   ctx2  = (u16*)(ws + 14010368);     //  2,621,440 B (total ~16.6 MB)

  float* outp     = (float*)d_out;
  float* attn_o   = outp + 1310720;
  float* scores_o = outp + 5505024;

  k_prep  <<<dim3(PY_BLK + WP_BLK + WO_BLK + WC_BLK), dim3(256), 0, stream>>>(
      Q, K, c1w, c1b, c2w, c2b, c1pw, c2pw, Wv, vfw, vfb, Wo,
      ypack, wp1, wp2, Wobf, WCbc);
  k_vst   <<<dim3(5120), dim3(256), 0, stream>>>(V, WCbc, vsT);
  k_scores<<<dim3(1024), dim3(1024), 0, stream>>>(ypack, wp1, c1pb, wp2, c2pb,
                                                  prev, vsT, attn_o, scores_o, ctx2);
  k_out   <<<dim3(256),  dim3(256), 0, stream>>>(ctx2, Wobf, outp);
}